// Round 1
// baseline (603.498 us; speedup 1.0000x reference)
//
#include <hip/hip_runtime.h>

typedef __attribute__((ext_vector_type(4))) float f32x4;
typedef __attribute__((ext_vector_type(8))) __bf16 bf16x8;

#define MFMA16(a, b, c) __builtin_amdgcn_mfma_f32_16x16x32_bf16(a, b, c, 0, 0, 0)

__device__ __forceinline__ void gload_lds16(const void* g, void* l) {
  __builtin_amdgcn_global_load_lds(
      (const __attribute__((address_space(1))) unsigned int*)g,
      (__attribute__((address_space(3))) unsigned int*)l, 16, 0, 0);
}

// ---------------------------------------------------------------------------
// Convert q,k,v fp32 -> bf16 (8M elems each). grid (4096, 3), block 256.
// ---------------------------------------------------------------------------
__global__ __launch_bounds__(256) void cvt3(
    const float* __restrict__ q, const float* __restrict__ k, const float* __restrict__ v,
    __bf16* __restrict__ qb, __bf16* __restrict__ kb, __bf16* __restrict__ vb) {
  const float* src;
  __bf16* dst;
  if (blockIdx.y == 0) { src = q; dst = qb; }
  else if (blockIdx.y == 1) { src = k; dst = kb; }
  else { src = v; dst = vb; }
  size_t i = ((size_t)blockIdx.x * 256 + threadIdx.x) * 8;
  float4 a = *(const float4*)(src + i);
  float4 b = *(const float4*)(src + i + 4);
  struct alignas(16) B8 { __bf16 h[8]; } ob;
  ob.h[0] = (__bf16)a.x; ob.h[1] = (__bf16)a.y; ob.h[2] = (__bf16)a.z; ob.h[3] = (__bf16)a.w;
  ob.h[4] = (__bf16)b.x; ob.h[5] = (__bf16)b.y; ob.h[6] = (__bf16)b.z; ob.h[7] = (__bf16)b.w;
  *(B8*)(dst + i) = ob;
}

// ---------------------------------------------------------------------------
// Transposed convert of a 1024x1024 weight: Wt[n][k] = (bf16)W[k][n].
// grid (16,16): blockIdx.x = n-tile, blockIdx.y = k-tile. block 256.
// ---------------------------------------------------------------------------
__global__ __launch_bounds__(256) void wtrans(const float* __restrict__ W,
                                              __bf16* __restrict__ Wt) {
  __shared__ float T[64][65];
  int t = threadIdx.x;
  int tc = blockIdx.x, tr = blockIdx.y;
#pragma unroll
  for (int i = 0; i < 4; i++) {
    int r = i * 16 + (t >> 4), c = (t & 15) * 4;
    float4 x = *(const float4*)(W + (size_t)(tr * 64 + r) * 1024 + tc * 64 + c);
    T[r][c] = x.x; T[r][c + 1] = x.y; T[r][c + 2] = x.z; T[r][c + 3] = x.w;
  }
  __syncthreads();
#pragma unroll
  for (int i = 0; i < 4; i++) {
    int r = i * 16 + (t >> 4), c = (t & 15) * 4;
    struct alignas(8) B4 { __bf16 h[4]; } ob;
#pragma unroll
    for (int j = 0; j < 4; j++) ob.h[j] = (__bf16)T[c + j][r];
    *(B4*)(Wt + (size_t)(tc * 64 + r) * 1024 + tr * 64 + c) = ob;
  }
}

// ---------------------------------------------------------------------------
// bf16 GEMM, m97 structure: C[M=8192][N=1024] = A[M][K=1024] * Bt[N][K]^T
// 128x128 tile, BK=32, 4 waves (each 64x64), global_load_lds width 16.
// MODE 0: write bf16 head-split layout [B][H][S][64].
// MODE 1: write fp32 out[row*1024+col] = acc + resid[row*1024+col].
// grid (N/128=8, M/128=64), block 256.
// ---------------------------------------------------------------------------
template <int MODE>
__global__ __launch_bounds__(256) void gemm_bt(
    const __bf16* __restrict__ A, const __bf16* __restrict__ Bt,
    const float* __restrict__ resid, __bf16* __restrict__ outb,
    float* __restrict__ outf) {
  constexpr int K = 1024;
  __shared__ __align__(16) __bf16 As[128 * 32];
  __shared__ __align__(16) __bf16 Bs[128 * 32];
  int t = threadIdx.x, lane = t & 63, w = t >> 6;
  int l15 = lane & 15, l4 = lane >> 4;
  int m0 = blockIdx.y * 128, n0 = blockIdx.x * 128;
  int wr = w >> 1, wc = w & 1;

  f32x4 z = {0.f, 0.f, 0.f, 0.f};
  f32x4 acc[4][4];
#pragma unroll
  for (int mi = 0; mi < 4; mi++)
#pragma unroll
    for (int ni = 0; ni < 4; ni++) acc[mi][ni] = z;

  int rA = t >> 2, cA = (t & 3) * 8;

  for (int kt = 0; kt < K / 32; ++kt) {
    __syncthreads();
    int k0 = kt * 32;
#pragma unroll
    for (int i = 0; i < 2; i++) {
      gload_lds16(A + (size_t)(m0 + i * 64 + rA) * K + k0 + cA, As + (i * 4 + w) * 512);
      gload_lds16(Bt + (size_t)(n0 + i * 64 + rA) * K + k0 + cA, Bs + (i * 4 + w) * 512);
    }
    __syncthreads();

    bf16x8 af[4], bfr[4];
#pragma unroll
    for (int mi = 0; mi < 4; mi++)
      af[mi] = *(const bf16x8*)(As + (wr * 64 + mi * 16 + l15) * 32 + l4 * 8);
#pragma unroll
    for (int ni = 0; ni < 4; ni++)
      bfr[ni] = *(const bf16x8*)(Bs + (wc * 64 + ni * 16 + l15) * 32 + l4 * 8);
#pragma unroll
    for (int mi = 0; mi < 4; mi++)
#pragma unroll
      for (int ni = 0; ni < 4; ni++)
        acc[mi][ni] = MFMA16(af[mi], bfr[ni], acc[mi][ni]);
  }

#pragma unroll
  for (int mi = 0; mi < 4; mi++)
#pragma unroll
    for (int ni = 0; ni < 4; ni++)
#pragma unroll
      for (int r = 0; r < 4; r++) {
        int row = m0 + wr * 64 + mi * 16 + l4 * 4 + r;
        int col = n0 + wc * 64 + ni * 16 + l15;
        if (MODE == 0) {
          int b = row >> 11, s = row & 2047, h = col >> 6, dk = col & 63;
          outb[(((size_t)b * 16 + h) * 2048 + s) * 64 + dk] = (__bf16)acc[mi][ni][r];
        } else {
          size_t idx = (size_t)row * 1024 + col;
          outf[idx] = acc[mi][ni][r] + resid[idx];
        }
      }
}

// ---------------------------------------------------------------------------
// Flash attention. QH/KH/VH: [B*H][S][64] bf16. AO: [B][S][H*64] bf16.
// grid (64, 32): x = b*16+h, y = q-tile (64 rows). block 256 (4 waves).
// Each wave owns 16 q-rows. Constant logit bias cancels in softmax -> dropped.
// ---------------------------------------------------------------------------
__global__ __launch_bounds__(256) void attn_fwd(
    const __bf16* __restrict__ QH, const __bf16* __restrict__ KH,
    const __bf16* __restrict__ VH, __bf16* __restrict__ AO) {
  constexpr int S = 2048;
  int bh = blockIdx.x;
  int qt = blockIdx.y;
  int t = threadIdx.x, lane = t & 63, w = t >> 6;
  int l15 = lane & 15, l4 = lane >> 4;

  __shared__ __align__(16) __bf16 Qs[64 * 72];
  __shared__ __align__(16) __bf16 Ks[64 * 72];
  __shared__ __align__(16) __bf16 Vt[64 * 72];
  __shared__ __align__(16) __bf16 Ps[4][16 * 72];

  const __bf16* Qp = QH + ((size_t)bh * S + qt * 64) * 64;
  const __bf16* Kp = KH + (size_t)bh * S * 64;
  const __bf16* Vp = VH + (size_t)bh * S * 64;

#pragma unroll
  for (int i = 0; i < 2; i++) {
    int f = (i * 256 + t) * 8, r = f >> 6, c = f & 63;
    *(uint4*)(&Qs[r * 72 + c]) = *(const uint4*)(Qp + r * 64 + c);
  }

  f32x4 z = {0.f, 0.f, 0.f, 0.f};
  f32x4 o[4];
  float mr[4], lr[4];
#pragma unroll
  for (int r = 0; r < 4; r++) { o[r] = z; mr[r] = -1e30f; lr[r] = 0.f; }

  for (int kt = 0; kt < 32; ++kt) {
    __syncthreads();
#pragma unroll
    for (int i = 0; i < 2; i++) {
      int f = (i * 256 + t) * 8, r = f >> 6, c = f & 63;
      *(uint4*)(&Ks[r * 72 + c]) = *(const uint4*)(Kp + (size_t)(kt * 64 + r) * 64 + c);
      uint4 vv = *(const uint4*)(Vp + (size_t)(kt * 64 + r) * 64 + c);
      const __bf16* ve = (const __bf16*)&vv;
#pragma unroll
      for (int j = 0; j < 8; j++) Vt[(c + j) * 72 + r] = ve[j];
    }
    __syncthreads();

    // S = Q * K^T for this wave's 16 rows x 64 cols
    f32x4 s4[4];
#pragma unroll
    for (int nf = 0; nf < 4; nf++) s4[nf] = z;
#pragma unroll
    for (int ks = 0; ks < 2; ++ks) {
      bf16x8 aq = *(const bf16x8*)(&Qs[(w * 16 + l15) * 72 + ks * 32 + l4 * 8]);
#pragma unroll
      for (int nf = 0; nf < 4; ++nf) {
        bf16x8 bk = *(const bf16x8*)(&Ks[(nf * 16 + l15) * 72 + ks * 32 + l4 * 8]);
        s4[nf] = MFMA16(aq, bk, s4[nf]);
      }
    }

    // online softmax (scaled by 1/8)
    float pm[4];
#pragma unroll
    for (int r = 0; r < 4; r++) {
      float v0 = fmaxf(fmaxf(s4[0][r], s4[1][r]), fmaxf(s4[2][r], s4[3][r])) * 0.125f;
#pragma unroll
      for (int d = 1; d < 16; d <<= 1) v0 = fmaxf(v0, __shfl_xor(v0, d));
      pm[r] = v0;
    }
    float corr[4], rs[4];
#pragma unroll
    for (int r = 0; r < 4; r++) {
      float mn = fmaxf(mr[r], pm[r]);
      corr[r] = __expf(mr[r] - mn);
      mr[r] = mn;
      rs[r] = 0.f;
    }
#pragma unroll
    for (int nf = 0; nf < 4; ++nf)
#pragma unroll
      for (int r = 0; r < 4; r++) {
        float p = __expf(s4[nf][r] * 0.125f - mr[r]);
        rs[r] += p;
        Ps[w][(l4 * 4 + r) * 72 + nf * 16 + l15] = (__bf16)p;
      }
#pragma unroll
    for (int r = 0; r < 4; r++) {
      float v0 = rs[r];
#pragma unroll
      for (int d = 1; d < 16; d <<= 1) v0 += __shfl_xor(v0, d);
      lr[r] = lr[r] * corr[r] + v0;
    }
#pragma unroll
    for (int nf = 0; nf < 4; nf++)
#pragma unroll
      for (int r = 0; r < 4; r++) o[nf][r] *= corr[r];

    // O += P * V
#pragma unroll
    for (int ks = 0; ks < 2; ++ks) {
      bf16x8 ap = *(const bf16x8*)(&Ps[w][l15 * 72 + ks * 32 + l4 * 8]);
#pragma unroll
      for (int nf = 0; nf < 4; ++nf) {
        bf16x8 bv = *(const bf16x8*)(&Vt[(nf * 16 + l15) * 72 + ks * 32 + l4 * 8]);
        o[nf] = MFMA16(ap, bv, o[nf]);
      }
    }
  }

  int b = bh >> 4, h = bh & 15;
#pragma unroll
  for (int nf = 0; nf < 4; nf++)
#pragma unroll
    for (int r = 0; r < 4; r++) {
      int row = qt * 64 + w * 16 + l4 * 4 + r;
      int col = h * 64 + nf * 16 + l15;
      AO[((size_t)b * S + row) * 1024 + col] = (__bf16)(o[nf][r] / lr[r]);
    }
}

// ---------------------------------------------------------------------------
// In-place LayerNorm over rows of 1024 fp32. grid 8192, block 256.
// ---------------------------------------------------------------------------
__global__ __launch_bounds__(256) void ln_inplace(float* __restrict__ X,
                                                  const float* __restrict__ gamma,
                                                  const float* __restrict__ beta) {
  int row = blockIdx.x, t = threadIdx.x;
  int w = t >> 6, lane = t & 63;
  float4 x = *(const float4*)(X + (size_t)row * 1024 + t * 4);
  float s = x.x + x.y + x.z + x.w;
#pragma unroll
  for (int d = 1; d < 64; d <<= 1) s += __shfl_xor(s, d);
  __shared__ float red1[4];
  __shared__ float red2[4];
  if (lane == 0) red1[w] = s;
  __syncthreads();
  float mean = (red1[0] + red1[1] + red1[2] + red1[3]) * (1.0f / 1024.0f);
  float4 d4;
  d4.x = x.x - mean; d4.y = x.y - mean; d4.z = x.z - mean; d4.w = x.w - mean;
  float sq = d4.x * d4.x + d4.y * d4.y + d4.z * d4.z + d4.w * d4.w;
#pragma unroll
  for (int d = 1; d < 64; d <<= 1) sq += __shfl_xor(sq, d);
  if (lane == 0) red2[w] = sq;
  __syncthreads();
  float var = (red2[0] + red2[1] + red2[2] + red2[3]) * (1.0f / 1024.0f);
  float rstd = rsqrtf(var + 1e-6f);
  float4 g = *(const float4*)(gamma + t * 4);
  float4 be = *(const float4*)(beta + t * 4);
  float4 oo;
  oo.x = d4.x * rstd * g.x + be.x;
  oo.y = d4.y * rstd * g.y + be.y;
  oo.z = d4.z * rstd * g.z + be.z;
  oo.w = d4.w * rstd * g.w + be.w;
  *(float4*)(X + (size_t)row * 1024 + t * 4) = oo;
}

// ---------------------------------------------------------------------------
extern "C" void kernel_launch(void* const* d_in, const int* in_sizes, int n_in,
                              void* d_out, int out_size, void* d_ws, size_t ws_size,
                              hipStream_t stream) {
  (void)in_sizes; (void)n_in; (void)out_size; (void)ws_size;
  const float* q = (const float*)d_in[0];
  const float* k = (const float*)d_in[1];
  const float* v = (const float*)d_in[2];
  const float* Wq = (const float*)d_in[3];
  const float* Wk = (const float*)d_in[4];
  const float* Wv = (const float*)d_in[5];
  const float* Wfc = (const float*)d_in[6];
  const float* gamma = (const float*)d_in[7];
  const float* beta = (const float*)d_in[8];
  float* out = (float*)d_out;

  const size_t MB = 1ull << 20;
  char* ws = (char*)d_ws;
  __bf16* qb = (__bf16*)(ws + 0 * MB);    // 16 MB
  __bf16* kb = (__bf16*)(ws + 16 * MB);   // 16 MB
  __bf16* vb = (__bf16*)(ws + 32 * MB);   // 16 MB
  __bf16* QH = (__bf16*)(ws + 48 * MB);   // 16 MB [B][H][S][64]
  __bf16* KH = (__bf16*)(ws + 64 * MB);   // 16 MB
  __bf16* VH = (__bf16*)(ws + 80 * MB);   // 16 MB
  __bf16* Wqt = (__bf16*)(ws + 96 * MB);  // 2 MB  [N][K]
  __bf16* Wkt = (__bf16*)(ws + 98 * MB);
  __bf16* Wvt = (__bf16*)(ws + 100 * MB);
  __bf16* Wfct = (__bf16*)(ws + 102 * MB);
  __bf16* AO = qb;  // alias: qb dead after QH projection

  cvt3<<<dim3(4096, 3), 256, 0, stream>>>(q, k, v, qb, kb, vb);
  wtrans<<<dim3(16, 16), 256, 0, stream>>>(Wq, Wqt);
  wtrans<<<dim3(16, 16), 256, 0, stream>>>(Wk, Wkt);
  wtrans<<<dim3(16, 16), 256, 0, stream>>>(Wv, Wvt);
  wtrans<<<dim3(16, 16), 256, 0, stream>>>(Wfc, Wfct);

  gemm_bt<0><<<dim3(8, 64), 256, 0, stream>>>(qb, Wqt, nullptr, QH, nullptr);
  gemm_bt<0><<<dim3(8, 64), 256, 0, stream>>>(kb, Wkt, nullptr, KH, nullptr);
  gemm_bt<0><<<dim3(8, 64), 256, 0, stream>>>(vb, Wvt, nullptr, VH, nullptr);

  attn_fwd<<<dim3(64, 32), 256, 0, stream>>>(QH, KH, VH, AO);

  gemm_bt<1><<<dim3(8, 64), 256, 0, stream>>>(AO, Wfct, q, nullptr, out);

  ln_inplace<<<8192, 256, 0, stream>>>(out, gamma, beta);
}